// Round 11
// baseline (266.526 us; speedup 1.0000x reference)
//
#include <hip/hip_runtime.h>
#include <math.h>

#define NV 100000
#define NE 3200000
#define NK 16
#define NT 4
#define NBK 64            // nodes per bucket (reduce)
#define NB 1563           // ceil(NV/64) buckets
#define NG 8              // writer groups (chunk & 7)
#define NBG (NB * NG)     // 12504 counters
#define BCAP 3072         // reduce chunk capacity (bucket mean ~2048 edges)
#define SCH 4096          // scatter chunk (edges per block)
#define NCHUNK ((NE + SCH - 1) / SCH)  // 782
#define PI_F 3.14159265358979323846f
#define LOG2E_F 1.4426950408889634f

// ---------------- fallback path (R1 atomic kernel) ----------------

__global__ __launch_bounds__(256) void zero_out_kernel(float4* __restrict__ out, int n4) {
    int i = blockIdx.x * blockDim.x + threadIdx.x;
    if (i < n4) out[i] = make_float4(0.f, 0.f, 0.f, 0.f);
}

__global__ __launch_bounds__(256) void atomic_conv_edge_kernel(
    const float* __restrict__ feat, const float* __restrict__ dist,
    const int* __restrict__ src, const int* __restrict__ dst,
    const float* __restrict__ cutoffs, const float* __restrict__ means,
    const float* __restrict__ scaling, const float* __restrict__ feats_use,
    float* __restrict__ out)
{
    int e = blockIdx.x * blockDim.x + threadIdx.x;
    if (e >= NE) return;
    float d = dist[e];
    int s = src[e];
    int v = dst[e];
    float fv = feat[s];
    int ty = 0;
#pragma unroll
    for (int t = 1; t < NT; ++t) if (fv == feats_use[t]) ty = t;
    float* o = out + (size_t)v * (NT * NK) + (size_t)ty * NK;
#pragma unroll
    for (int k = 0; k < NK; ++k) {
        float c = cutoffs[k], m = means[k], sc = scaling[k];
        float dm = d - m;
        float rbf = __expf(-sc * dm * dm);
        float cosv = 0.5f * (__cosf(PI_F * d / c) + 1.0f);
        float he = (d <= c) ? rbf * cosv : 0.0f;
        __hip_atomic_fetch_add(o + k, he, __ATOMIC_RELAXED, __HIP_MEMORY_SCOPE_AGENT);
    }
}

// ---------------- bucket-sort + owner-compute reduce path ----------------

// per-chunk histogram with the EXACT same chunk->group mapping as scatter_kernel:
// chunk c covers edges [c*SCH, c*SCH+SCH), group g = c & 7.
__global__ __launch_bounds__(256) void hist_kernel(const int4* __restrict__ dst4,
                                                   int* __restrict__ counts) {
    __shared__ int h[NB];
    for (int i = threadIdx.x; i < NB; i += 256) h[i] = 0;
    __syncthreads();
    const int nqTot = NE / 4;                 // 800000 quads
    int q0 = blockIdx.x * (SCH / 4);          // 1024 quads per chunk
    int nq = nqTot - q0;
    if (nq > SCH / 4) nq = SCH / 4;
    for (int i = threadIdx.x; i < nq; i += 256) {
        int4 v = dst4[q0 + i];
        atomicAdd(&h[v.x >> 6], 1);
        atomicAdd(&h[v.y >> 6], 1);
        atomicAdd(&h[v.z >> 6], 1);
        atomicAdd(&h[v.w >> 6], 1);
    }
    __syncthreads();
    int g = blockIdx.x & (NG - 1);
    for (int i = threadIdx.x; i < NB; i += 256) {
        int c = h[i];
        if (c) atomicAdd(&counts[i * NG + g], c);
    }
}

__global__ __launch_bounds__(1024) void scan_kernel(const int* __restrict__ counts,
                                                    int* __restrict__ offsets,
                                                    int* __restrict__ cursors) {
    __shared__ int s[1024];
    const int CH = (NBG + 1023) / 1024;  // 13
    int t = threadIdx.x;
    int base = t * CH;
    int loc[CH];
    int sum = 0;
#pragma unroll
    for (int i = 0; i < CH; ++i) {
        int idx = base + i;
        int v = (idx < NBG) ? counts[idx] : 0;
        loc[i] = sum;
        sum += v;
    }
    s[t] = sum;
    __syncthreads();
#pragma unroll
    for (int off = 1; off < 1024; off <<= 1) {
        int v = (t >= off) ? s[t - off] : 0;
        __syncthreads();
        s[t] += v;
        __syncthreads();
    }
    int excl = (t > 0) ? s[t - 1] : 0;
#pragma unroll
    for (int i = 0; i < CH; ++i) {
        int idx = base + i;
        if (idx < NBG) {
            int o = excl + loc[i];
            offsets[idx] = o;
            cursors[idx] = o;
        }
    }
    if (t == 1023) offsets[NBG] = NE;
}

// block-aggregated scatter: one cursor atomic per (bucket, block).
// chunk c covers edges [c*SCH, c*SCH+SCH), group g = c & 7 — MUST match hist_kernel.
// bucket id recomputed in the write pass by re-reading dst (L2-hit) — no bkt[] LDS.
__global__ __launch_bounds__(256) void scatter_kernel(
    const float* __restrict__ feat, const float* __restrict__ dist,
    const int* __restrict__ src, const int* __restrict__ dst,
    const float* __restrict__ feats_use,
    int* __restrict__ cursors, unsigned* __restrict__ payload)
{
    __shared__ unsigned pld[SCH];
    __shared__ int hist[NB];
    __shared__ int base[NB];

    int t = threadIdx.x;
    int g = blockIdx.x & (NG - 1);
    int chunkBase = blockIdx.x * SCH;
    int n = NE - chunkBase;
    if (n > SCH) n = SCH;

    float f1 = feats_use[1], f2 = feats_use[2], f3 = feats_use[3];

    for (int i = t; i < NB; i += 256) hist[i] = 0;
    __syncthreads();

    for (int i = t; i < n; i += 256) {
        int e = chunkBase + i;
        float d = dist[e];
        int s = src[e];
        int v = dst[e];
        float fv = feat[s];
        int ty = (fv == f1) ? 1 : (fv == f2) ? 2 : (fv == f3) ? 3 : 0;
        // [31:9]=top 23 bits of d | [7:0]=key=(ldst<<2)|ty
        unsigned packed = (__float_as_uint(d) & 0xFFFFFE00u) |
                          ((unsigned)(v & 63) << 2) | (unsigned)ty;
        pld[i] = packed;
        atomicAdd(&hist[v >> 6], 1);
    }
    __syncthreads();

    for (int i = t; i < NB; i += 256) {
        int c = hist[i];
        base[i] = c ? __hip_atomic_fetch_add(&cursors[i * NG + g], c,
                                             __ATOMIC_RELAXED, __HIP_MEMORY_SCOPE_AGENT)
                    : 0;
        hist[i] = 0;  // reuse as block-local cursor
    }
    __syncthreads();

    for (int i = t; i < n; i += 256) {
        int b = dst[chunkBase + i] >> 6;   // re-read (coalesced, L2-hit)
        int lp = atomicAdd(&hist[b], 1);
        payload[base[b] + lp] = pld[i];
    }
}

// one block per 64-node bucket: LDS counting sort by key=(ldst<<2)|ty, then
// thread t owns key t = (node, type) -> 16 register accs, no atomics in hot loop.
__global__ __launch_bounds__(256) void reduce_kernel(
    const unsigned* __restrict__ payload, const int* __restrict__ offsets,
    const float* __restrict__ cutoffs, const float* __restrict__ means,
    const float* __restrict__ scaling, float* __restrict__ out)
{
    __shared__ unsigned raw[BCAP];
    __shared__ unsigned srt[BCAP];
    __shared__ int scn[256];
    __shared__ int cur[256];
    __shared__ int coff[257];

    int b = blockIdx.x;
    int t = threadIdx.x;
    int s0 = offsets[b * NG];
    int s1 = offsets[(b + 1) * NG];

    float m_[NK], c1_[NK];
    bool uniformC = true;
#pragma unroll
    for (int k = 0; k < NK; ++k) {
        m_[k] = means[k];
        c1_[k] = -scaling[k] * LOG2E_F;   // exp(-s x) == exp2(c1 x)
        uniformC = uniformC && (cutoffs[k] == cutoffs[0]);
    }
    float c0 = cutoffs[0];
    float w0 = PI_F / c0;

    float acc[NK];
#pragma unroll
    for (int k = 0; k < NK; ++k) acc[k] = 0.f;

    for (int base = s0; base < s1; base += BCAP) {
        int n = s1 - base;
        if (n > BCAP) n = BCAP;

        for (int i = t; i < n; i += 256) raw[i] = payload[base + i];
        scn[t] = 0;
        __syncthreads();

        for (int i = t; i < n; i += 256) {
            int key = raw[i] & 255;
            atomicAdd(&scn[key], 1);
        }
        __syncthreads();

        int x = scn[t];
#pragma unroll
        for (int off2 = 1; off2 < 256; off2 <<= 1) {
            int v = (t >= off2) ? scn[t - off2] : 0;
            __syncthreads();
            scn[t] += v;
            __syncthreads();
        }
        int excl = scn[t] - x;
        coff[t] = excl;
        cur[t] = excl;
        if (t == 0) coff[256] = n;
        __syncthreads();

        for (int i = t; i < n; i += 256) {
            unsigned p = raw[i];
            int key = p & 255;
            int pos = atomicAdd(&cur[key], 1);
            srt[pos] = p;
        }
        __syncthreads();

        int e0 = coff[t];
        int e1 = coff[t + 1];
        if (uniformC) {
#pragma unroll 2
            for (int i = e0; i < e1; ++i) {
                unsigned p = srt[i];
                float d = __uint_as_float(p & 0xFFFFFE00u);
                float cv = 0.5f * (__cosf(w0 * d) + 1.0f);
                cv = (d <= c0) ? cv : 0.0f;
#pragma unroll
                for (int k = 0; k < NK; ++k) {
                    float dm = d - m_[k];
                    float e = exp2f(c1_[k] * (dm * dm));
                    acc[k] = fmaf(e, cv, acc[k]);
                }
            }
        } else {
            for (int i = e0; i < e1; ++i) {
                unsigned p = srt[i];
                float d = __uint_as_float(p & 0xFFFFFE00u);
#pragma unroll
                for (int k = 0; k < NK; ++k) {
                    float dm = d - m_[k];
                    float rbf = __expf(-scaling[k] * dm * dm);
                    float cosv = 0.5f * (__cosf(PI_F * d / cutoffs[k]) + 1.0f);
                    float he = (d <= cutoffs[k]) ? rbf * cosv : 0.0f;
                    acc[k] += he;
                }
            }
        }
        __syncthreads();
    }

    int node = b * NBK + (t >> 2);
    if (node < NV) {
        int ty = t & 3;
        float4* o = (float4*)(out + (size_t)node * 64 + ty * 16);
#pragma unroll
        for (int k = 0; k < 4; ++k)
            o[k] = make_float4(acc[4 * k], acc[4 * k + 1], acc[4 * k + 2], acc[4 * k + 3]);
    }
}

extern "C" void kernel_launch(void* const* d_in, const int* in_sizes, int n_in,
                              void* d_out, int out_size, void* d_ws, size_t ws_size,
                              hipStream_t stream) {
    const float* feat      = (const float*)d_in[0];
    const float* dist      = (const float*)d_in[1];
    const int*   src       = (const int*)d_in[2];
    const int*   dst       = (const int*)d_in[3];
    const float* cutoffs   = (const float*)d_in[4];
    const float* means     = (const float*)d_in[5];
    const float* scaling   = (const float*)d_in[6];
    const float* feats_use = (const float*)d_in[7];
    float* out = (float*)d_out;

    size_t off = 0;
    auto alloc = [&](size_t bytes) {
        size_t cur = off;
        off = (off + bytes + 255) & ~(size_t)255;
        return cur;
    };
    size_t o_counts  = alloc((size_t)NBG * 4);
    size_t o_offsets = alloc((size_t)(NBG + 1) * 4);
    size_t o_cursors = alloc((size_t)NBG * 4);
    size_t o_payload = alloc((size_t)NE * 4);
    size_t needed = off;

    if (ws_size < needed) {
        int n4 = out_size / 4;
        zero_out_kernel<<<(n4 + 255) / 256, 256, 0, stream>>>((float4*)out, n4);
        atomic_conv_edge_kernel<<<(NE + 255) / 256, 256, 0, stream>>>(
            feat, dist, src, dst, cutoffs, means, scaling, feats_use, out);
        return;
    }

    char* ws = (char*)d_ws;
    int* counts  = (int*)(ws + o_counts);
    int* offsets = (int*)(ws + o_offsets);
    int* cursors = (int*)(ws + o_cursors);
    unsigned* payload = (unsigned*)(ws + o_payload);

    hipMemsetAsync(counts, 0, (size_t)NBG * 4, stream);

    hist_kernel<<<NCHUNK, 256, 0, stream>>>((const int4*)dst, counts);

    scan_kernel<<<1, 1024, 0, stream>>>(counts, offsets, cursors);

    scatter_kernel<<<NCHUNK, 256, 0, stream>>>(
        feat, dist, src, dst, feats_use, cursors, payload);

    reduce_kernel<<<NB, 256, 0, stream>>>(
        payload, offsets, cutoffs, means, scaling, out);
}

// Round 12
// 234.788 us; speedup vs baseline: 1.1352x; 1.1352x over previous
//
#include <hip/hip_runtime.h>
#include <math.h>

#define NV 100000
#define NE 3200000
#define NK 16
#define NT 4
#define NBK 64            // nodes per bucket (reduce)
#define NB 1563           // ceil(NV/64) buckets
#define NG 8              // writer groups (chunk & 7)
#define NBG (NB * NG)     // 12504 counters
#define BCAP 3072         // reduce chunk capacity (bucket mean ~2048 edges)
#define SCH 8192          // scatter chunk (edges per block) — big runs, low fragmentation
#define NCHUNK ((NE + SCH - 1) / SCH)  // 391
#define PI_F 3.14159265358979323846f
#define LOG2E_F 1.4426950408889634f

// ---------------- fallback path (R1 atomic kernel) ----------------

__global__ __launch_bounds__(256) void zero_out_kernel(float4* __restrict__ out, int n4) {
    int i = blockIdx.x * blockDim.x + threadIdx.x;
    if (i < n4) out[i] = make_float4(0.f, 0.f, 0.f, 0.f);
}

__global__ __launch_bounds__(256) void atomic_conv_edge_kernel(
    const float* __restrict__ feat, const float* __restrict__ dist,
    const int* __restrict__ src, const int* __restrict__ dst,
    const float* __restrict__ cutoffs, const float* __restrict__ means,
    const float* __restrict__ scaling, const float* __restrict__ feats_use,
    float* __restrict__ out)
{
    int e = blockIdx.x * blockDim.x + threadIdx.x;
    if (e >= NE) return;
    float d = dist[e];
    int s = src[e];
    int v = dst[e];
    float fv = feat[s];
    int ty = 0;
#pragma unroll
    for (int t = 1; t < NT; ++t) if (fv == feats_use[t]) ty = t;
    float* o = out + (size_t)v * (NT * NK) + (size_t)ty * NK;
#pragma unroll
    for (int k = 0; k < NK; ++k) {
        float c = cutoffs[k], m = means[k], sc = scaling[k];
        float dm = d - m;
        float rbf = __expf(-sc * dm * dm);
        float cosv = 0.5f * (__cosf(PI_F * d / c) + 1.0f);
        float he = (d <= c) ? rbf * cosv : 0.0f;
        __hip_atomic_fetch_add(o + k, he, __ATOMIC_RELAXED, __HIP_MEMORY_SCOPE_AGENT);
    }
}

// ---------------- bucket-sort + owner-compute reduce path ----------------

// per-chunk histogram with the EXACT same chunk->group mapping as scatter_kernel:
// chunk c covers edges [c*SCH, c*SCH+SCH), group g = c & 7.
__global__ __launch_bounds__(256) void hist_kernel(const int4* __restrict__ dst4,
                                                   int* __restrict__ counts) {
    __shared__ int h[NB];
    for (int i = threadIdx.x; i < NB; i += 256) h[i] = 0;
    __syncthreads();
    const int nqTot = NE / 4;                 // 800000 quads
    int q0 = blockIdx.x * (SCH / 4);          // 2048 quads per chunk
    int nq = nqTot - q0;
    if (nq > SCH / 4) nq = SCH / 4;
    for (int i = threadIdx.x; i < nq; i += 256) {
        int4 v = dst4[q0 + i];
        atomicAdd(&h[v.x >> 6], 1);
        atomicAdd(&h[v.y >> 6], 1);
        atomicAdd(&h[v.z >> 6], 1);
        atomicAdd(&h[v.w >> 6], 1);
    }
    __syncthreads();
    int g = blockIdx.x & (NG - 1);
    for (int i = threadIdx.x; i < NB; i += 256) {
        int c = h[i];
        if (c) atomicAdd(&counts[i * NG + g], c);
    }
}

__global__ __launch_bounds__(1024) void scan_kernel(const int* __restrict__ counts,
                                                    int* __restrict__ offsets,
                                                    int* __restrict__ cursors) {
    __shared__ int s[1024];
    const int CH = (NBG + 1023) / 1024;  // 13
    int t = threadIdx.x;
    int base = t * CH;
    int loc[CH];
    int sum = 0;
#pragma unroll
    for (int i = 0; i < CH; ++i) {
        int idx = base + i;
        int v = (idx < NBG) ? counts[idx] : 0;
        loc[i] = sum;
        sum += v;
    }
    s[t] = sum;
    __syncthreads();
#pragma unroll
    for (int off = 1; off < 1024; off <<= 1) {
        int v = (t >= off) ? s[t - off] : 0;
        __syncthreads();
        s[t] += v;
        __syncthreads();
    }
    int excl = (t > 0) ? s[t - 1] : 0;
#pragma unroll
    for (int i = 0; i < CH; ++i) {
        int idx = base + i;
        if (idx < NBG) {
            int o = excl + loc[i];
            offsets[idx] = o;
            cursors[idx] = o;
        }
    }
    if (t == 1023) offsets[NBG] = NE;
}

// block-aggregated scatter: one cursor atomic per (bucket, block).
// chunk c covers edges [c*SCH, c*SCH+SCH), group g = c & 7 — MUST match hist_kernel.
// bucket id recomputed in the write pass by re-reading dst (L2-hit) — no bkt[] LDS.
__global__ __launch_bounds__(256) void scatter_kernel(
    const float* __restrict__ feat, const float* __restrict__ dist,
    const int* __restrict__ src, const int* __restrict__ dst,
    const float* __restrict__ feats_use,
    int* __restrict__ cursors, unsigned* __restrict__ payload)
{
    __shared__ unsigned pld[SCH];   // 32 KB
    __shared__ int hist[NB];        // 6.25 KB
    __shared__ int base[NB];        // 6.25 KB   -> total ~44.7 KB, 3 blocks/CU

    int t = threadIdx.x;
    int g = blockIdx.x & (NG - 1);
    int chunkBase = blockIdx.x * SCH;
    int n = NE - chunkBase;
    if (n > SCH) n = SCH;

    float f1 = feats_use[1], f2 = feats_use[2], f3 = feats_use[3];

    for (int i = t; i < NB; i += 256) hist[i] = 0;
    __syncthreads();

    for (int i = t; i < n; i += 256) {
        int e = chunkBase + i;
        float d = dist[e];
        int s = src[e];
        int v = dst[e];
        float fv = feat[s];
        int ty = (fv == f1) ? 1 : (fv == f2) ? 2 : (fv == f3) ? 3 : 0;
        // [31:9]=top 23 bits of d | [7:0]=key=(ldst<<2)|ty
        unsigned packed = (__float_as_uint(d) & 0xFFFFFE00u) |
                          ((unsigned)(v & 63) << 2) | (unsigned)ty;
        pld[i] = packed;
        atomicAdd(&hist[v >> 6], 1);
    }
    __syncthreads();

    for (int i = t; i < NB; i += 256) {
        int c = hist[i];
        base[i] = c ? __hip_atomic_fetch_add(&cursors[i * NG + g], c,
                                             __ATOMIC_RELAXED, __HIP_MEMORY_SCOPE_AGENT)
                    : 0;
        hist[i] = 0;  // reuse as block-local cursor
    }
    __syncthreads();

    for (int i = t; i < n; i += 256) {
        int b = dst[chunkBase + i] >> 6;   // re-read (coalesced, L2-hit)
        int lp = atomicAdd(&hist[b], 1);
        payload[base[b] + lp] = pld[i];
    }
}

// one block per 64-node bucket: LDS counting sort by key=(ldst<<2)|ty, then
// thread t owns key t = (node, type) -> 16 register accs, no atomics in hot loop.
__global__ __launch_bounds__(256) void reduce_kernel(
    const unsigned* __restrict__ payload, const int* __restrict__ offsets,
    const float* __restrict__ cutoffs, const float* __restrict__ means,
    const float* __restrict__ scaling, float* __restrict__ out)
{
    __shared__ unsigned raw[BCAP];
    __shared__ unsigned srt[BCAP];
    __shared__ int scn[256];
    __shared__ int cur[256];
    __shared__ int coff[257];

    int b = blockIdx.x;
    int t = threadIdx.x;
    int s0 = offsets[b * NG];
    int s1 = offsets[(b + 1) * NG];

    float m_[NK], c1_[NK];
    bool uniformC = true;
#pragma unroll
    for (int k = 0; k < NK; ++k) {
        m_[k] = means[k];
        c1_[k] = -scaling[k] * LOG2E_F;   // exp(-s x) == exp2(c1 x)
        uniformC = uniformC && (cutoffs[k] == cutoffs[0]);
    }
    float c0 = cutoffs[0];
    float w0 = PI_F / c0;

    float acc[NK];
#pragma unroll
    for (int k = 0; k < NK; ++k) acc[k] = 0.f;

    for (int base = s0; base < s1; base += BCAP) {
        int n = s1 - base;
        if (n > BCAP) n = BCAP;

        for (int i = t; i < n; i += 256) raw[i] = payload[base + i];
        scn[t] = 0;
        __syncthreads();

        for (int i = t; i < n; i += 256) {
            int key = raw[i] & 255;
            atomicAdd(&scn[key], 1);
        }
        __syncthreads();

        int x = scn[t];
#pragma unroll
        for (int off2 = 1; off2 < 256; off2 <<= 1) {
            int v = (t >= off2) ? scn[t - off2] : 0;
            __syncthreads();
            scn[t] += v;
            __syncthreads();
        }
        int excl = scn[t] - x;
        coff[t] = excl;
        cur[t] = excl;
        if (t == 0) coff[256] = n;
        __syncthreads();

        for (int i = t; i < n; i += 256) {
            unsigned p = raw[i];
            int key = p & 255;
            int pos = atomicAdd(&cur[key], 1);
            srt[pos] = p;
        }
        __syncthreads();

        int e0 = coff[t];
        int e1 = coff[t + 1];
        if (uniformC) {
#pragma unroll 2
            for (int i = e0; i < e1; ++i) {
                unsigned p = srt[i];
                float d = __uint_as_float(p & 0xFFFFFE00u);
                float cv = 0.5f * (__cosf(w0 * d) + 1.0f);
                cv = (d <= c0) ? cv : 0.0f;
#pragma unroll
                for (int k = 0; k < NK; ++k) {
                    float dm = d - m_[k];
                    float e = exp2f(c1_[k] * (dm * dm));
                    acc[k] = fmaf(e, cv, acc[k]);
                }
            }
        } else {
            for (int i = e0; i < e1; ++i) {
                unsigned p = srt[i];
                float d = __uint_as_float(p & 0xFFFFFE00u);
#pragma unroll
                for (int k = 0; k < NK; ++k) {
                    float dm = d - m_[k];
                    float rbf = __expf(-scaling[k] * dm * dm);
                    float cosv = 0.5f * (__cosf(PI_F * d / cutoffs[k]) + 1.0f);
                    float he = (d <= cutoffs[k]) ? rbf * cosv : 0.0f;
                    acc[k] += he;
                }
            }
        }
        __syncthreads();
    }

    int node = b * NBK + (t >> 2);
    if (node < NV) {
        int ty = t & 3;
        float4* o = (float4*)(out + (size_t)node * 64 + ty * 16);
#pragma unroll
        for (int k = 0; k < 4; ++k)
            o[k] = make_float4(acc[4 * k], acc[4 * k + 1], acc[4 * k + 2], acc[4 * k + 3]);
    }
}

extern "C" void kernel_launch(void* const* d_in, const int* in_sizes, int n_in,
                              void* d_out, int out_size, void* d_ws, size_t ws_size,
                              hipStream_t stream) {
    const float* feat      = (const float*)d_in[0];
    const float* dist      = (const float*)d_in[1];
    const int*   src       = (const int*)d_in[2];
    const int*   dst       = (const int*)d_in[3];
    const float* cutoffs   = (const float*)d_in[4];
    const float* means     = (const float*)d_in[5];
    const float* scaling   = (const float*)d_in[6];
    const float* feats_use = (const float*)d_in[7];
    float* out = (float*)d_out;

    size_t off = 0;
    auto alloc = [&](size_t bytes) {
        size_t cur = off;
        off = (off + bytes + 255) & ~(size_t)255;
        return cur;
    };
    size_t o_counts  = alloc((size_t)NBG * 4);
    size_t o_offsets = alloc((size_t)(NBG + 1) * 4);
    size_t o_cursors = alloc((size_t)NBG * 4);
    size_t o_payload = alloc((size_t)NE * 4);
    size_t needed = off;

    if (ws_size < needed) {
        int n4 = out_size / 4;
        zero_out_kernel<<<(n4 + 255) / 256, 256, 0, stream>>>((float4*)out, n4);
        atomic_conv_edge_kernel<<<(NE + 255) / 256, 256, 0, stream>>>(
            feat, dist, src, dst, cutoffs, means, scaling, feats_use, out);
        return;
    }

    char* ws = (char*)d_ws;
    int* counts  = (int*)(ws + o_counts);
    int* offsets = (int*)(ws + o_offsets);
    int* cursors = (int*)(ws + o_cursors);
    unsigned* payload = (unsigned*)(ws + o_payload);

    hipMemsetAsync(counts, 0, (size_t)NBG * 4, stream);

    hist_kernel<<<NCHUNK, 256, 0, stream>>>((const int4*)dst, counts);

    scan_kernel<<<1, 1024, 0, stream>>>(counts, offsets, cursors);

    scatter_kernel<<<NCHUNK, 256, 0, stream>>>(
        feat, dist, src, dst, feats_use, cursors, payload);

    reduce_kernel<<<NB, 256, 0, stream>>>(
        payload, offsets, cutoffs, means, scaling, out);
}

// Round 13
// 218.332 us; speedup vs baseline: 1.2207x; 1.0754x over previous
//
#include <hip/hip_runtime.h>
#include <math.h>

#define NV 100000
#define NE 3200000
#define NK 16
#define NT 4
#define NBK 64            // nodes per bucket (reduce)
#define NB 1563           // ceil(NV/64) buckets
#define BCAP 3072         // reduce chunk capacity (bucket mean ~2048 edges)
#define SCH 8192          // sort chunk (edges per chunk)
#define NCHUNK ((NE + SCH - 1) / SCH)  // 391
#define NW 6250           // type words: 16 nodes x 2 bits each
#define PI_F 3.14159265358979323846f
#define LOG2E_F 1.4426950408889634f

// ---------------- fallback path (R1 atomic kernel) ----------------

__global__ __launch_bounds__(256) void zero_out_kernel(float4* __restrict__ out, int n4) {
    int i = blockIdx.x * blockDim.x + threadIdx.x;
    if (i < n4) out[i] = make_float4(0.f, 0.f, 0.f, 0.f);
}

__global__ __launch_bounds__(256) void atomic_conv_edge_kernel(
    const float* __restrict__ feat, const float* __restrict__ dist,
    const int* __restrict__ src, const int* __restrict__ dst,
    const float* __restrict__ cutoffs, const float* __restrict__ means,
    const float* __restrict__ scaling, const float* __restrict__ feats_use,
    float* __restrict__ out)
{
    int e = blockIdx.x * blockDim.x + threadIdx.x;
    if (e >= NE) return;
    float d = dist[e];
    int s = src[e];
    int v = dst[e];
    float fv = feat[s];
    int ty = 0;
#pragma unroll
    for (int t = 1; t < NT; ++t) if (fv == feats_use[t]) ty = t;
    float* o = out + (size_t)v * (NT * NK) + (size_t)ty * NK;
#pragma unroll
    for (int k = 0; k < NK; ++k) {
        float c = cutoffs[k], m = means[k], sc = scaling[k];
        float dm = d - m;
        float rbf = __expf(-sc * dm * dm);
        float cosv = 0.5f * (__cosf(PI_F * d / c) + 1.0f);
        float he = (d <= c) ? rbf * cosv : 0.0f;
        __hip_atomic_fetch_add(o + k, he, __ATOMIC_RELAXED, __HIP_MEMORY_SCOPE_AGENT);
    }
}

// ---------------- deterministic counting-sort (zero global atomics) ----------------

// 2-bit type code per node, 16 nodes per u32 word -> 24.4 KB L1-resident table
__global__ __launch_bounds__(256) void pack_types_kernel(
    const float* __restrict__ feat, const float* __restrict__ feats_use,
    unsigned* __restrict__ types)
{
    int w = blockIdx.x * 256 + threadIdx.x;
    if (w >= NW) return;
    float f1 = feats_use[1], f2 = feats_use[2], f3 = feats_use[3];
    unsigned word = 0;
#pragma unroll
    for (int j = 0; j < 16; ++j) {
        int v = w * 16 + j;
        unsigned code = 0;
        if (v < NV) {
            float fv = feat[v];
            code = (fv == f1) ? 1u : (fv == f2) ? 2u : (fv == f3) ? 3u : 0u;
        }
        word |= code << (2 * j);
    }
    types[w] = word;
}

// per-chunk LDS histogram -> plain coalesced stores counts[c*NB + b] (covers all b, no memset)
__global__ __launch_bounds__(256) void hist_kernel(const int4* __restrict__ dst4,
                                                   int* __restrict__ counts) {
    __shared__ int h[NB];
    for (int i = threadIdx.x; i < NB; i += 256) h[i] = 0;
    __syncthreads();
    const int nqTot = NE / 4;
    int q0 = blockIdx.x * (SCH / 4);
    int nq = nqTot - q0;
    if (nq > SCH / 4) nq = SCH / 4;
    for (int i = threadIdx.x; i < nq; i += 256) {
        int4 v = dst4[q0 + i];
        atomicAdd(&h[v.x >> 6], 1);
        atomicAdd(&h[v.y >> 6], 1);
        atomicAdd(&h[v.z >> 6], 1);
        atomicAdd(&h[v.w >> 6], 1);
    }
    __syncthreads();
    int c = blockIdx.x;
    for (int i = threadIdx.x; i < NB; i += 256) counts[(size_t)c * NB + i] = h[i];
}

// per-bucket serial scan over chunks in XCD-group-major order (c%8 outer):
// counts[c*NB+b] -> in-place exclusive prefix pfx; totals[b] = bucket total.
// Coalesced across threads (consecutive b).
__global__ __launch_bounds__(256) void scanA_kernel(int* __restrict__ counts,
                                                    int* __restrict__ totals) {
    int b = blockIdx.x * 256 + threadIdx.x;
    if (b >= NB) return;
    int run = 0;
    for (int g = 0; g < 8; ++g) {
        for (int c = g; c < NCHUNK; c += 8) {
            int idx = c * NB + b;
            int v = counts[idx];
            counts[idx] = run;
            run += v;
        }
    }
    totals[b] = run;
}

// single-block exclusive scan of totals[NB] -> Boff[NB], Boff[NB] = NE
__global__ __launch_bounds__(1024) void scanB_kernel(const int* __restrict__ totals,
                                                     int* __restrict__ Boff) {
    __shared__ int s[1024];
    int t = threadIdx.x;
    int i0 = 2 * t, i1 = 2 * t + 1;
    int v0 = (i0 < NB) ? totals[i0] : 0;
    int v1 = (i1 < NB) ? totals[i1] : 0;
    int sum = v0 + v1;
    s[t] = sum;
    __syncthreads();
#pragma unroll
    for (int off = 1; off < 1024; off <<= 1) {
        int v = (t >= off) ? s[t - off] : 0;
        __syncthreads();
        s[t] += v;
        __syncthreads();
    }
    int excl = s[t] - sum;
    if (i0 < NB) Boff[i0] = excl;
    if (i1 < NB) Boff[i1] = excl + v0;
    if (t == 1023) Boff[NB] = NE;
}

// single-pass scatter: deterministic base from Boff+pfx, LDS cursor only (6.25 KB)
__global__ __launch_bounds__(256) void scatter_kernel(
    const unsigned* __restrict__ types, const float* __restrict__ dist,
    const int* __restrict__ src, const int* __restrict__ dst,
    const int* __restrict__ pfx, const int* __restrict__ Boff,
    unsigned* __restrict__ payload)
{
    __shared__ int cur[NB];
    int t = threadIdx.x;
    int c = blockIdx.x;
    int chunkBase = c * SCH;
    int n = NE - chunkBase;
    if (n > SCH) n = SCH;

    for (int i = t; i < NB; i += 256)
        cur[i] = Boff[i] + pfx[(size_t)c * NB + i];
    __syncthreads();

    for (int i = t; i < n; i += 256) {
        int e = chunkBase + i;
        float d = dist[e];
        int s = src[e];
        int v = dst[e];
        unsigned code = (types[s >> 4] >> ((s & 15) << 1)) & 3u;
        // [31:9]=top 23 bits of d | [7:0]=key=(ldst<<2)|ty
        unsigned packed = (__float_as_uint(d) & 0xFFFFFE00u) |
                          ((unsigned)(v & 63) << 2) | code;
        int lp = atomicAdd(&cur[v >> 6], 1);
        payload[lp] = packed;
    }
}

// one block per 64-node bucket: LDS counting sort by key=(ldst<<2)|ty, then
// thread t owns key t = (node, type) -> 16 register accs, no atomics in hot loop.
__global__ __launch_bounds__(256) void reduce_kernel(
    const unsigned* __restrict__ payload, const int* __restrict__ Boff,
    const float* __restrict__ cutoffs, const float* __restrict__ means,
    const float* __restrict__ scaling, float* __restrict__ out)
{
    __shared__ unsigned raw[BCAP];
    __shared__ unsigned srt[BCAP];
    __shared__ int scn[256];
    __shared__ int cur[256];
    __shared__ int coff[257];

    int b = blockIdx.x;
    int t = threadIdx.x;
    int s0 = Boff[b];
    int s1 = Boff[b + 1];

    float m_[NK], c1_[NK];
    bool uniformC = true;
#pragma unroll
    for (int k = 0; k < NK; ++k) {
        m_[k] = means[k];
        c1_[k] = -scaling[k] * LOG2E_F;   // exp(-s x) == exp2(c1 x)
        uniformC = uniformC && (cutoffs[k] == cutoffs[0]);
    }
    float c0 = cutoffs[0];
    float w0 = PI_F / c0;

    float acc[NK];
#pragma unroll
    for (int k = 0; k < NK; ++k) acc[k] = 0.f;

    for (int base = s0; base < s1; base += BCAP) {
        int n = s1 - base;
        if (n > BCAP) n = BCAP;

        for (int i = t; i < n; i += 256) raw[i] = payload[base + i];
        scn[t] = 0;
        __syncthreads();

        for (int i = t; i < n; i += 256) {
            int key = raw[i] & 255;
            atomicAdd(&scn[key], 1);
        }
        __syncthreads();

        int x = scn[t];
#pragma unroll
        for (int off2 = 1; off2 < 256; off2 <<= 1) {
            int v = (t >= off2) ? scn[t - off2] : 0;
            __syncthreads();
            scn[t] += v;
            __syncthreads();
        }
        int excl = scn[t] - x;
        coff[t] = excl;
        cur[t] = excl;
        if (t == 0) coff[256] = n;
        __syncthreads();

        for (int i = t; i < n; i += 256) {
            unsigned p = raw[i];
            int key = p & 255;
            int pos = atomicAdd(&cur[key], 1);
            srt[pos] = p;
        }
        __syncthreads();

        int e0 = coff[t];
        int e1 = coff[t + 1];
        if (uniformC) {
#pragma unroll 2
            for (int i = e0; i < e1; ++i) {
                unsigned p = srt[i];
                float d = __uint_as_float(p & 0xFFFFFE00u);
                float cv = 0.5f * (__cosf(w0 * d) + 1.0f);
                cv = (d <= c0) ? cv : 0.0f;
#pragma unroll
                for (int k = 0; k < NK; ++k) {
                    float dm = d - m_[k];
                    float e = exp2f(c1_[k] * (dm * dm));
                    acc[k] = fmaf(e, cv, acc[k]);
                }
            }
        } else {
            for (int i = e0; i < e1; ++i) {
                unsigned p = srt[i];
                float d = __uint_as_float(p & 0xFFFFFE00u);
#pragma unroll
                for (int k = 0; k < NK; ++k) {
                    float dm = d - m_[k];
                    float rbf = __expf(-scaling[k] * dm * dm);
                    float cosv = 0.5f * (__cosf(PI_F * d / cutoffs[k]) + 1.0f);
                    float he = (d <= cutoffs[k]) ? rbf * cosv : 0.0f;
                    acc[k] += he;
                }
            }
        }
        __syncthreads();
    }

    int node = b * NBK + (t >> 2);
    if (node < NV) {
        int ty = t & 3;
        float4* o = (float4*)(out + (size_t)node * 64 + ty * 16);
#pragma unroll
        for (int k = 0; k < 4; ++k)
            o[k] = make_float4(acc[4 * k], acc[4 * k + 1], acc[4 * k + 2], acc[4 * k + 3]);
    }
}

extern "C" void kernel_launch(void* const* d_in, const int* in_sizes, int n_in,
                              void* d_out, int out_size, void* d_ws, size_t ws_size,
                              hipStream_t stream) {
    const float* feat      = (const float*)d_in[0];
    const float* dist      = (const float*)d_in[1];
    const int*   src       = (const int*)d_in[2];
    const int*   dst       = (const int*)d_in[3];
    const float* cutoffs   = (const float*)d_in[4];
    const float* means     = (const float*)d_in[5];
    const float* scaling   = (const float*)d_in[6];
    const float* feats_use = (const float*)d_in[7];
    float* out = (float*)d_out;

    size_t off = 0;
    auto alloc = [&](size_t bytes) {
        size_t cur = off;
        off = (off + bytes + 255) & ~(size_t)255;
        return cur;
    };
    size_t o_types   = alloc((size_t)NW * 4);
    size_t o_counts  = alloc((size_t)NCHUNK * NB * 4);   // counts -> pfx in-place
    size_t o_totals  = alloc((size_t)NB * 4);
    size_t o_Boff    = alloc((size_t)(NB + 1) * 4);
    size_t o_payload = alloc((size_t)NE * 4);
    size_t needed = off;

    if (ws_size < needed) {
        int n4 = out_size / 4;
        zero_out_kernel<<<(n4 + 255) / 256, 256, 0, stream>>>((float4*)out, n4);
        atomic_conv_edge_kernel<<<(NE + 255) / 256, 256, 0, stream>>>(
            feat, dist, src, dst, cutoffs, means, scaling, feats_use, out);
        return;
    }

    char* ws = (char*)d_ws;
    unsigned* types  = (unsigned*)(ws + o_types);
    int* counts      = (int*)(ws + o_counts);
    int* totals      = (int*)(ws + o_totals);
    int* Boff        = (int*)(ws + o_Boff);
    unsigned* payload = (unsigned*)(ws + o_payload);

    pack_types_kernel<<<(NW + 255) / 256, 256, 0, stream>>>(feat, feats_use, types);

    hist_kernel<<<NCHUNK, 256, 0, stream>>>((const int4*)dst, counts);

    scanA_kernel<<<(NB + 255) / 256, 256, 0, stream>>>(counts, totals);
    scanB_kernel<<<1, 1024, 0, stream>>>(totals, Boff);

    scatter_kernel<<<NCHUNK, 256, 0, stream>>>(
        types, dist, src, dst, counts, Boff, payload);

    reduce_kernel<<<NB, 256, 0, stream>>>(
        payload, Boff, cutoffs, means, scaling, out);
}